// Round 4
// baseline (547.554 us; speedup 1.0000x reference)
//
#include <hip/hip_runtime.h>

#define M_DIM 8192
#define N_DIM 4096
#define K_DIM 4096

typedef _Float16 f16;
typedef _Float16 f16x8 __attribute__((ext_vector_type(8)));
typedef float f32x4 __attribute__((ext_vector_type(4)));

// async global->LDS, 16B per lane. LDS dest is wave-uniform base; HW stores lane i at base + i*16.
__device__ __forceinline__ void lds_async16(void* lds, const void* g) {
    __builtin_amdgcn_global_load_lds(
        (const __attribute__((address_space(1))) void*)(void*)g,
        (__attribute__((address_space(3))) void*)lds, 16, 0, 0);
}

// ---- prepass: fp32 x -> f16 (8 floats / thread) ----
__global__ __launch_bounds__(256) void cvt_x_kernel(const float* __restrict__ x, f16* __restrict__ xh) {
    size_t idx  = (size_t)blockIdx.x * 256 + threadIdx.x;
    size_t base = idx * 8;
    const float4* xp = (const float4*)(x + base);
    float4 v0 = xp[0], v1 = xp[1];
    f16x8 h;
    h[0] = (f16)v0.x; h[1] = (f16)v0.y; h[2] = (f16)v0.z; h[3] = (f16)v0.w;
    h[4] = (f16)v1.x; h[5] = (f16)v1.y; h[6] = (f16)v1.z; h[7] = (f16)v1.w;
    *(f16x8*)(xh + base) = h;
}

// ---- prepass: packed int4 (one byte per int32, hi nibble first) -> f16 Q in [-8,7] ----
__global__ __launch_bounds__(256) void cvt_w_kernel(const int* __restrict__ pw, f16* __restrict__ wh) {
    size_t idx = (size_t)blockIdx.x * 256 + threadIdx.x;  // 4 ints / thread -> 8 halves
    int4 v = ((const int4*)pw)[idx];
    f16x8 h;
    int a;
    a = v.x; h[0] = (f16)(((a >> 4) & 15) - 8); h[1] = (f16)((a & 15) - 8);
    a = v.y; h[2] = (f16)(((a >> 4) & 15) - 8); h[3] = (f16)((a & 15) - 8);
    a = v.z; h[4] = (f16)(((a >> 4) & 15) - 8); h[5] = (f16)((a & 15) - 8);
    a = v.w; h[6] = (f16)(((a >> 4) & 15) - 8); h[7] = (f16)((a & 15) - 8);
    *(f16x8*)(wh + idx * 8) = h;
}

// ---- main GEMM: m201/m204 256^2 8-phase template, race-free stage schedule ----
// BM=BN=256, BK=64, 8 waves (2M x 4N), per-wave output 128x64, mfma_f32_16x16x32_f16.
// LDS 128 KiB: [2 dbuf][2 M-or-N-half][128 rows][64 halves] per operand. st_16x32 swizzle:
// content (r, u16B) stored at slot u ^ (((r>>2)&1)<<1).
// Staging: linear LDS dest (global_load_lds), inverse-swizzled global source.
//
// Phase schedule per K-tile T (current buf cb = T&1, other buf = T+1's):
//   ph0: read aF0(8) + bF0(4); stage (T+1, B-h1) [other buf];  MFMA C(0,0)
//   ph1: read bF1(4);          stage (T+1, A-h1) [other buf];  MFMA C(0,1)
//   ph2: read aF1(8);          stage (T+2, B-h0) [cur: B halves drained at ph1];  MFMA C(1,1)
//   ph3: no reads;             stage (T+2, A-h0) [cur: A halves drained at ph2];  MFMA C(1,0)
//        vmcnt(4); barrier
// Safety invariant: per-phase lgkmcnt(0) precedes the phase-end barrier, so a half staged
// at phase p only overwrites rows whose last ds_read was at phase <= p-1. (R3's bug:
// A-h0 staged at ph1 while wm=0 waves still read it at ph2.)
// Ledger (2 loads/stage): at T ph3, issued = 12 + 8(T+1); tile T+1's last load (A-h1 @ T ph1)
// has index 8T+16 = issued-4 -> vmcnt(4). Loads stay 2-6 phases in flight, never drained to 0.
// Tail: stage targets >= 64 redirect to a 2 KB LDS scratch sink (keeps ledger uniform).
__global__ __launch_bounds__(512, 2) void gemm_f16(const f16* __restrict__ A, const f16* __restrict__ B,
                                                   const int* __restrict__ pb,
                                                   const float* __restrict__ psw, const float* __restrict__ psb,
                                                   float* __restrict__ out) {
    __shared__ f16 AS[2][2][8192];   // [buf][M-half][r*64+c] : 64 KB
    __shared__ f16 BS[2][2][8192];   // [buf][N-half][...]    : 64 KB
    __shared__ f16 SCR[1024];        // 2 KB dummy DMA sink for tail-ledger prefetches

    const int tid  = threadIdx.x;
    const int w    = tid >> 6;           // wave 0..7
    const int lane = tid & 63;
    const int l16  = lane & 15;
    const int lq   = lane >> 4;          // 0..3
    const int wm   = w >> 2;             // A-half (M): 0..1
    const int wn   = w & 3;              // N quarter: 0..3
    const int hb   = wn >> 1;            // B-half (N)

    // XCD-bijective block swizzle: 512 wgs, 8 XCDs, 64 per XCD
    const int bid = blockIdx.x;
    const int swz = (bid & 7) * 64 + (bid >> 3);
    const int bx  = swz & 15;            // 16 N-tiles
    const int by  = swz >> 4;            // 32 M-tiles
    const int mbase = by * 256;
    const int nbase = bx * 256;

    // ---- staging source addresses (inverse st_16x32 swizzle; dest is linear lane*16B) ----
    // instr (wave w, j) covers rows w*16 + j*8 + (lane>>3); lane stores slot (lane&7);
    // slot u_s holds content u = u_s ^ (((r>>2)&1)<<1); bit2 of r == (lane>>5)&1.
    const int uL = (lane & 7) ^ (((lane >> 5) & 1) << 1);
    const f16* aSrc00 = A + (size_t)(mbase + w * 16 + (lane >> 3)) * K_DIM + uL * 8;
    const f16* aSrc01 = aSrc00 + (size_t)8 * K_DIM;
    const f16* aSrc10 = aSrc00 + (size_t)128 * K_DIM;
    const f16* aSrc11 = aSrc10 + (size_t)8 * K_DIM;
    const f16* bSrc00 = B + (size_t)(nbase + w * 16 + (lane >> 3)) * K_DIM + uL * 8;
    const f16* bSrc01 = bSrc00 + (size_t)8 * K_DIM;
    const f16* bSrc10 = bSrc00 + (size_t)128 * K_DIM;
    const f16* bSrc11 = bSrc10 + (size_t)8 * K_DIM;
    const int wb = w * 1024;             // LDS dest (halves) for this wave's j=0 instr; j=1 at +512

// kind: 0=A-h0, 1=B-h0, 2=A-h1, 3=B-h1. tidx uniform; tidx>63 -> dummy to scratch (keeps vmcnt ledger).
#define STAGE_KIND(tidx, kind) do {                                                              \
    if ((tidx) < 64) {                                                                           \
        const int b_ = (tidx) & 1;                                                               \
        if ((kind) == 0) { lds_async16(&AS[b_][0][wb], aSrc00 + (tidx) * 64);                    \
                           lds_async16(&AS[b_][0][wb + 512], aSrc01 + (tidx) * 64); }            \
        else if ((kind) == 1) { lds_async16(&BS[b_][0][wb], bSrc00 + (tidx) * 64);               \
                                lds_async16(&BS[b_][0][wb + 512], bSrc01 + (tidx) * 64); }       \
        else if ((kind) == 2) { lds_async16(&AS[b_][1][wb], aSrc10 + (tidx) * 64);               \
                                lds_async16(&AS[b_][1][wb + 512], aSrc11 + (tidx) * 64); }       \
        else { lds_async16(&BS[b_][1][wb], bSrc10 + (tidx) * 64);                                \
               lds_async16(&BS[b_][1][wb + 512], bSrc11 + (tidx) * 64); }                        \
    } else {                                                                                     \
        lds_async16(&SCR[0], aSrc00 + 4032); lds_async16(&SCR[512], aSrc01 + 4032);              \
    }                                                                                            \
} while (0)

    // ---- fragment read addresses (halves). frag (row-frag fi, kstep s): row r, k-unit u = s*4+lq;
    // swizzled slot = s*4 + (lq ^ xr(r)); addr = r*64 + slot*8 = base + s*32. ----
    int aAd[2][4];   // [mq][fi]
#pragma unroll
    for (int mq = 0; mq < 2; mq++)
#pragma unroll
        for (int fi = 0; fi < 4; fi++) {
            const int r  = mq * 64 + fi * 16 + l16;
            const int xr = ((r >> 2) & 1) << 1;
            aAd[mq][fi]  = r * 64 + ((lq ^ xr) << 3);
        }
    int bAd[2][2];   // [nq][gi]
#pragma unroll
    for (int nq = 0; nq < 2; nq++)
#pragma unroll
        for (int gi = 0; gi < 2; gi++) {
            const int r  = (wn & 1) * 64 + nq * 32 + gi * 16 + l16;
            const int xr = ((r >> 2) & 1) << 1;
            bAd[nq][gi]  = r * 64 + ((lq ^ xr) << 3);
        }

    f32x4 acc[8][4] = {};   // [fi' = mq*4+fi][gj' = nq*2+gi]

    // ---- prologue: tile0 all 4 kinds; tile1 {B-h0, A-h0}; vmcnt(4) -> tile0 landed; barrier ----
    STAGE_KIND(0, 0); STAGE_KIND(0, 1); STAGE_KIND(0, 2); STAGE_KIND(0, 3);
    STAGE_KIND(1, 1); STAGE_KIND(1, 0);
    asm volatile("s_waitcnt vmcnt(4)" ::: "memory");
    __builtin_amdgcn_s_barrier();

#pragma unroll 1
    for (int T = 0; T < 64; ++T) {
        const int cb = T & 1;
        const f16* Ah = &AS[cb][wm][0];
        const f16* Bh = &BS[cb][hb][0];
        f16x8 aF0[4][2], aF1[4][2], bF0[2][2], bF1[2][2];

        // ---- phase 0: read aF0(8) + bF0(4); stage (T+1, B-h1) [other buf]; MFMA C(0,0) ----
#pragma unroll
        for (int fi = 0; fi < 4; fi++)
#pragma unroll
            for (int s = 0; s < 2; s++) aF0[fi][s] = *(const f16x8*)&Ah[aAd[0][fi] + s * 32];
#pragma unroll
        for (int gi = 0; gi < 2; gi++)
#pragma unroll
            for (int s = 0; s < 2; s++) bF0[gi][s] = *(const f16x8*)&Bh[bAd[0][gi] + s * 32];
        STAGE_KIND(T + 1, 3);
        asm volatile("s_waitcnt lgkmcnt(8)" ::: "memory");
        __builtin_amdgcn_s_barrier();
        asm volatile("s_waitcnt lgkmcnt(0)" ::: "memory");
        __builtin_amdgcn_sched_barrier(0);
        __builtin_amdgcn_s_setprio(1);
#pragma unroll
        for (int s = 0; s < 2; s++)
#pragma unroll
            for (int fi = 0; fi < 4; fi++)
#pragma unroll
                for (int gi = 0; gi < 2; gi++)
                    acc[fi][gi] = __builtin_amdgcn_mfma_f32_16x16x32_f16(aF0[fi][s], bF0[gi][s], acc[fi][gi], 0, 0, 0);
        __builtin_amdgcn_s_setprio(0);
        __builtin_amdgcn_s_barrier();

        // ---- phase 1: read bF1(4); stage (T+1, A-h1) [other buf]; MFMA C(0,1) ----
#pragma unroll
        for (int gi = 0; gi < 2; gi++)
#pragma unroll
            for (int s = 0; s < 2; s++) bF1[gi][s] = *(const f16x8*)&Bh[bAd[1][gi] + s * 32];
        STAGE_KIND(T + 1, 2);
        __builtin_amdgcn_s_barrier();
        asm volatile("s_waitcnt lgkmcnt(0)" ::: "memory");
        __builtin_amdgcn_sched_barrier(0);
        __builtin_amdgcn_s_setprio(1);
#pragma unroll
        for (int s = 0; s < 2; s++)
#pragma unroll
            for (int fi = 0; fi < 4; fi++)
#pragma unroll
                for (int gi = 0; gi < 2; gi++)
                    acc[fi][2 + gi] = __builtin_amdgcn_mfma_f32_16x16x32_f16(aF0[fi][s], bF1[gi][s], acc[fi][2 + gi], 0, 0, 0);
        __builtin_amdgcn_s_setprio(0);
        __builtin_amdgcn_s_barrier();

        // ---- phase 2: read aF1(8); stage (T+2, B-h0) [cur buf: B halves drained at ph1]; MFMA C(1,1) ----
#pragma unroll
        for (int fi = 0; fi < 4; fi++)
#pragma unroll
            for (int s = 0; s < 2; s++) aF1[fi][s] = *(const f16x8*)&Ah[aAd[1][fi] + s * 32];
        STAGE_KIND(T + 2, 1);
        __builtin_amdgcn_s_barrier();
        asm volatile("s_waitcnt lgkmcnt(0)" ::: "memory");
        __builtin_amdgcn_sched_barrier(0);
        __builtin_amdgcn_s_setprio(1);
#pragma unroll
        for (int s = 0; s < 2; s++)
#pragma unroll
            for (int fi = 0; fi < 4; fi++)
#pragma unroll
                for (int gi = 0; gi < 2; gi++)
                    acc[4 + fi][2 + gi] = __builtin_amdgcn_mfma_f32_16x16x32_f16(aF1[fi][s], bF1[gi][s], acc[4 + fi][2 + gi], 0, 0, 0);
        __builtin_amdgcn_s_setprio(0);
        __builtin_amdgcn_s_barrier();

        // ---- phase 3: no reads; stage (T+2, A-h0) [cur buf: A halves drained at ph2]; MFMA C(1,0) ----
        STAGE_KIND(T + 2, 0);
        __builtin_amdgcn_s_barrier();
        asm volatile("s_waitcnt lgkmcnt(0)" ::: "memory");
        __builtin_amdgcn_sched_barrier(0);
        __builtin_amdgcn_s_setprio(1);
#pragma unroll
        for (int s = 0; s < 2; s++)
#pragma unroll
            for (int fi = 0; fi < 4; fi++)
#pragma unroll
                for (int gi = 0; gi < 2; gi++)
                    acc[4 + fi][gi] = __builtin_amdgcn_mfma_f32_16x16x32_f16(aF1[fi][s], bF0[gi][s], acc[4 + fi][gi], 0, 0, 0);
        __builtin_amdgcn_s_setprio(0);
        asm volatile("s_waitcnt vmcnt(4)" ::: "memory");   // tile T+1 fully landed (its last load is issued-4)
        __builtin_amdgcn_s_barrier();
    }

    asm volatile("s_waitcnt vmcnt(0)" ::: "memory");   // drain tail dummies before LDS dealloc

    const float sw = *psw;
    const float sb = *psb;

    // C/D layout (m89/m91, 16x16): col = lane&15, row = (lane>>4)*4 + reg
#pragma unroll
    for (int gj = 0; gj < 4; gj++) {
        const int gcol = nbase + wn * 64 + gj * 16 + l16;
        const int p    = pb[gcol >> 1];
        const int nib  = (gcol & 1) ? (p & 15) : ((p >> 4) & 15);
        const float bias = sb * (float)(nib - 8);
#pragma unroll
        for (int fi = 0; fi < 8; fi++) {
            const int grow = mbase + wm * 128 + fi * 16 + lq * 4;
            float* o = out + (size_t)grow * N_DIM + gcol;
#pragma unroll
            for (int r = 0; r < 4; r++)
                o[(size_t)r * N_DIM] = sw * acc[fi][gj][r] + bias;
        }
    }
#undef STAGE_KIND
}

// ---- correct-but-slow fallback if workspace is too small for the f16 copies ----
__global__ __launch_bounds__(256) void gemm_fallback(const float* __restrict__ x, const int* __restrict__ pw,
                                                     const int* __restrict__ pb,
                                                     const float* __restrict__ psw, const float* __restrict__ psb,
                                                     float* __restrict__ out) {
    __shared__ float As[16][17];
    __shared__ float Bs[16][17];
    const int tx = threadIdx.x & 15, ty = threadIdx.x >> 4;
    const int row = blockIdx.y * 16 + ty;   // m
    const int col = blockIdx.x * 16 + tx;   // n
    float acc = 0.f;
    for (int k0 = 0; k0 < K_DIM; k0 += 16) {
        As[ty][tx] = x[(size_t)row * K_DIM + k0 + tx];
        const int nrow = blockIdx.x * 16 + ty;
        const int k = k0 + tx;
        const int p = pw[((size_t)nrow * K_DIM + k) >> 1];
        const int nib = (k & 1) ? (p & 15) : ((p >> 4) & 15);
        Bs[ty][tx] = (float)(nib - 8);
        __syncthreads();
#pragma unroll
        for (int kk = 0; kk < 16; kk++)
            acc += As[ty][kk] * Bs[tx][kk];
        __syncthreads();
    }
    const float sw = *psw, sb = *psb;
    const int p = pb[col >> 1];
    const int nib = (col & 1) ? (p & 15) : ((p >> 4) & 15);
    out[(size_t)row * N_DIM + col] = sw * acc + sb * (float)(nib - 8);
}

extern "C" void kernel_launch(void* const* d_in, const int* in_sizes, int n_in,
                              void* d_out, int out_size, void* d_ws, size_t ws_size,
                              hipStream_t stream) {
    (void)in_sizes; (void)n_in; (void)out_size;
    const float* x   = (const float*)d_in[0];
    const int*   pw  = (const int*)d_in[1];
    const int*   pb  = (const int*)d_in[2];
    const float* psw = (const float*)d_in[3];
    const float* psb = (const float*)d_in[4];
    float* out = (float*)d_out;

    const size_t xh_bytes = (size_t)M_DIM * K_DIM * sizeof(f16);   // 67.1 MB
    const size_t wh_bytes = (size_t)N_DIM * K_DIM * sizeof(f16);   // 33.6 MB

    if (ws_size >= xh_bytes + wh_bytes) {
        f16* xh = (f16*)d_ws;
        f16* wh = (f16*)((char*)d_ws + xh_bytes);
        cvt_x_kernel<<<(M_DIM * (size_t)K_DIM) / 8 / 256, 256, 0, stream>>>(x, xh);
        cvt_w_kernel<<<((size_t)N_DIM * K_DIM / 2) / 4 / 256, 256, 0, stream>>>(pw, wh);
        gemm_f16<<<dim3((M_DIM / 256) * (N_DIM / 256)), 512, 0, stream>>>(xh, wh, pb, psw, psb, out);
    } else {
        gemm_fallback<<<dim3(N_DIM / 16, M_DIM / 16), 256, 0, stream>>>(x, pw, pb, psw, psb, out);
    }
}